// Round 6
// baseline (225.123 us; speedup 1.0000x reference)
//
#include <hip/hip_runtime.h>
#include <math.h>

// Problem constants (from reference setup_inputs)
#define BATCH   2
#define NBOX    512
#define KTOT    (BATCH * NBOX)   // 1024 ROIs
#define CCH     256
#define OUTHW   7
#define PIX     (OUTHW * OUTHW)  // 49
#define TSTR    260              // stage LDS tile stride (u16): 520B rows -> bank-stride 2, 8B-aligned

typedef unsigned int u32;
typedef unsigned short u16;
typedef float  vf2 __attribute__((ext_vector_type(2)));   // native vector: ok for nontemporal builtins

__device__ __forceinline__ u16 f32_to_bf16(float f) {
    u32 u = __float_as_uint(f);
    u32 r = (u + 0x7fffu + ((u >> 16) & 1u)) >> 16;   // RNE
    return (u16)r;
}

// ===================== fallback (round-1 kernel, no ws needed) =====================
__global__ __launch_bounds__(256) void msroi_fallback(
    const float* __restrict__ f0, const float* __restrict__ f1,
    const float* __restrict__ f2, const float* __restrict__ f3,
    const float* __restrict__ boxes, float* __restrict__ out)
{
    const int t = blockIdx.x * blockDim.x + threadIdx.x;
    const int total = KTOT * CCH * PIX;
    if (t >= total) return;

    const int p  = t % PIX;
    const int c  = (t / PIX) % CCH;
    const int k  = t / (PIX * CCH);
    const int ph = p / OUTHW;
    const int pw = p % OUTHW;

    const float bx1 = boxes[k * 4 + 0];
    const float by1 = boxes[k * 4 + 1];
    const float bx2 = boxes[k * 4 + 2];
    const float by2 = boxes[k * 4 + 3];

    const float area = fmaxf((bx2 - bx1) * (by2 - by1), 0.0f);
    const float s    = sqrtf(area);
    float lvlf = floorf(4.0f + log2f(s / 224.0f) + 1e-6f);
    lvlf = fminf(fmaxf(lvlf, 2.0f), 5.0f);
    const int lvl = (int)lvlf - 2;

    const float* feat; int H, W; float scale;
    switch (lvl) {
        case 0:  feat = f0; H = 200; W = 200; scale = 0.25f;    break;
        case 1:  feat = f1; H = 100; W = 100; scale = 0.125f;   break;
        case 2:  feat = f2; H =  50; W =  50; scale = 0.0625f;  break;
        default: feat = f3; H =  25; W =  25; scale = 0.03125f; break;
    }

    const int b = k / NBOX;
    const float* __restrict__ fc = feat + ((size_t)(b * CCH + c)) * (size_t)(H * W);

    const float rx1 = bx1 * scale, ry1 = by1 * scale;
    const float rx2 = bx2 * scale, ry2 = by2 * scale;
    const float bin_w = fmaxf(rx2 - rx1, 1.0f) / (float)OUTHW;
    const float bin_h = fmaxf(ry2 - ry1, 1.0f) / (float)OUTHW;
    const float Hf = (float)H, Wf = (float)W;

    float acc = 0.0f;
    #pragma unroll
    for (int sy = 0; sy < 2; ++sy) {
        const float y  = ry1 + (float)ph * bin_h + ((float)sy + 0.5f) * bin_h / 2.0f;
        const bool  vy = (y >= -1.0f) && (y <= Hf);
        const float yc = fminf(fmaxf(y, 0.0f), Hf - 1.0f);
        int yl = (int)yc; if (yl > H - 2) yl = H - 2;
        const float ly = yc - (float)yl;
        #pragma unroll
        for (int sx = 0; sx < 2; ++sx) {
            const float x  = rx1 + (float)pw * bin_w + ((float)sx + 0.5f) * bin_w / 2.0f;
            const bool  vx = (x >= -1.0f) && (x <= Wf);
            const float xc = fminf(fmaxf(x, 0.0f), Wf - 1.0f);
            int xl = (int)xc; if (xl > W - 2) xl = W - 2;
            const float lx = xc - (float)xl;
            if (vy && vx) {
                const float* p00 = fc + (size_t)yl * W + xl;
                acc += (1.0f - ly) * (1.0f - lx) * p00[0]
                     + (1.0f - ly) * lx          * p00[1]
                     + ly          * (1.0f - lx) * p00[W]
                     + ly          * lx          * p00[W + 1];
            }
        }
    }
    out[t] = acc * 0.25f;
}

// ===================== fast path =====================

// ONE kernel: blocks 0..1663 transpose NCHW fp32 -> NHWC bf16 (64-spatial x 256-ch tiles);
// block 1664 bitonic-sorts ROIs by (level, qy, qx) for L2 locality.
#define TILES_L0 625
#define TILES_L1 157
#define TILES_L2 40
#define TILES_L3 10
#define TILES_PB (TILES_L0 + TILES_L1 + TILES_L2 + TILES_L3)   // 832
#define STAGE_BLOCKS (2 * TILES_PB + 1)                        // 1665

__global__ __launch_bounds__(256) void stage_and_sort(
    const float* __restrict__ f0, const float* __restrict__ f1,
    const float* __restrict__ f2, const float* __restrict__ f3,
    u16* __restrict__ g0, u16* __restrict__ g1,
    u16* __restrict__ g2, u16* __restrict__ g3,
    const float* __restrict__ boxes, u32* __restrict__ perm)
{
    __shared__ u32 ldsw[64 * TSTR / 2];          // 33,280 B
    const int id  = (int)blockIdx.x;
    const int tid = (int)threadIdx.x;

    if (id == 2 * TILES_PB) {
        // ---- sort block ----
        u32* key = ldsw;                          // 4 KB of the tile
        for (int i = tid; i < KTOT; i += 256) {
            const float bx1 = boxes[4 * i + 0];
            const float by1 = boxes[4 * i + 1];
            const float bx2 = boxes[4 * i + 2];
            const float by2 = boxes[4 * i + 3];
            const float area = fmaxf((bx2 - bx1) * (by2 - by1), 0.0f);
            const float s    = sqrtf(area);
            float lvlf = floorf(4.0f + log2f(s / 224.0f) + 1e-6f);
            lvlf = fminf(fmaxf(lvlf, 2.0f), 5.0f);
            const u32 lvl = (u32)((int)lvlf - 2);
            const float cx = 0.5f * (bx1 + bx2);
            const float cy = 0.5f * (by1 + by2);
            const u32 qx = (u32)min(511, max(0, (int)(cx * 0.64f)));
            const u32 qy = (u32)min(511, max(0, (int)(cy * 0.64f)));
            key[i] = (lvl << 28) | (qy << 19) | (qx << 10) | (u32)i;
        }
        __syncthreads();
        for (int kk = 2; kk <= KTOT; kk <<= 1) {
            for (int j = kk >> 1; j > 0; j >>= 1) {
                for (int i = tid; i < KTOT; i += 256) {
                    const int ixj = i ^ j;
                    if (ixj > i) {
                        const u32 a = key[i], b = key[ixj];
                        const bool up = ((i & kk) == 0);
                        if ((a > b) == up) { key[i] = b; key[ixj] = a; }
                    }
                }
                __syncthreads();
            }
        }
        for (int i = tid; i < KTOT; i += 256) perm[i] = key[i] & 1023u;
        return;
    }

    // ---- transpose tile ----
    const int b = id / TILES_PB;
    const int r = id % TILES_PB;
    const float* src; u16* dst; int S, t0;
    if (r < TILES_L0)                       { src = f0; dst = g0; S = 40000; t0 = r; }
    else if (r < TILES_L0 + TILES_L1)       { src = f1; dst = g1; S = 10000; t0 = r - TILES_L0; }
    else if (r < TILES_L0 + TILES_L1 + TILES_L2) { src = f2; dst = g2; S = 2500; t0 = r - TILES_L0 - TILES_L1; }
    else                                    { src = f3; dst = g3; S = 625;  t0 = r - TILES_L0 - TILES_L1 - TILES_L2; }

    u16* tile = reinterpret_cast<u16*>(ldsw);
    const int tx = tid & 63;
    const int ty = tid >> 6;
    const int s0 = t0 * 64;
    const int s  = s0 + tx;

    if (s < S) {
        const float* sp = src + (size_t)b * CCH * (size_t)S + s;
        #pragma unroll 8
        for (int cc = 0; cc < 64; ++cc) {
            const int c = ty * 64 + cc;
            tile[tx * TSTR + c] = f32_to_bf16(__builtin_nontemporal_load(&sp[(size_t)c * S]));
        }
    }
    __syncthreads();

    u16* dp = dst + (size_t)b * (size_t)S * CCH;
    #pragma unroll
    for (int it = 0; it < 16; ++it) {
        const int row = it * 4 + ty;
        const int ss  = s0 + row;
        if (ss < S) {
            const uint2 v = reinterpret_cast<const uint2*>(tile + row * TSTR)[tx];
            reinterpret_cast<uint2*>(dp + (size_t)ss * CCH)[tx] = v;
        }
    }
}

__device__ __forceinline__ void accum8(float* acc, float w, uint4 q) {
    acc[0] = fmaf(w, __uint_as_float(q.x << 16),          acc[0]);
    acc[1] = fmaf(w, __uint_as_float(q.x & 0xffff0000u),  acc[1]);
    acc[2] = fmaf(w, __uint_as_float(q.y << 16),          acc[2]);
    acc[3] = fmaf(w, __uint_as_float(q.y & 0xffff0000u),  acc[3]);
    acc[4] = fmaf(w, __uint_as_float(q.z << 16),          acc[4]);
    acc[5] = fmaf(w, __uint_as_float(q.z & 0xffff0000u),  acc[5]);
    acc[6] = fmaf(w, __uint_as_float(q.w << 16),          acc[6]);
    acc[7] = fmaf(w, __uint_as_float(q.w & 0xffff0000u),  acc[7]);
}

// One ROI per block. Half-wave (32 lanes) = one pixel, lanes = channel octets
// (32 x 16B = full 512B NHWC bf16 row). Output transposed to NCHW via a
// channel-major bf16 LDS tile (25 KB -> 6 blocks/CU).
__global__ __launch_bounds__(256, 6) void msroi_gather_bf16(
    const u16* __restrict__ g0, const u16* __restrict__ g1,
    const u16* __restrict__ g2, const u16* __restrict__ g3,
    const float* __restrict__ boxes, const u32* __restrict__ perm,
    float* __restrict__ out)
{
    __shared__ u32 tilew[(CCH * PIX) / 2];       // 25,088 B, bf16 c-major [256][49]
    u16* tile = reinterpret_cast<u16*>(tilew);

    const int bid  = (int)blockIdx.x;
    const int sidx = ((bid & 7) << 7) | (bid >> 3);   // XCD gets contiguous sorted chunk
    const int k    = (int)perm[sidx];

    const int tid  = (int)threadIdx.x;
    const int lane = tid & 63;
    const int wave = tid >> 6;
    const int half = lane >> 5;
    const int c0   = (lane & 31) * 8;   // channel octet base

    // per-ROI params (wave-uniform)
    const float bx1 = boxes[4 * k + 0];
    const float by1 = boxes[4 * k + 1];
    const float bx2 = boxes[4 * k + 2];
    const float by2 = boxes[4 * k + 3];

    const float area = fmaxf((bx2 - bx1) * (by2 - by1), 0.0f);
    const float s    = sqrtf(area);
    float lvlf = floorf(4.0f + log2f(s / 224.0f) + 1e-6f);
    lvlf = fminf(fmaxf(lvlf, 2.0f), 5.0f);
    const int lvl = (int)lvlf - 2;

    const u16* g; int H, W; float scale;
    switch (lvl) {
        case 0:  g = g0; H = 200; W = 200; scale = 0.25f;    break;
        case 1:  g = g1; H = 100; W = 100; scale = 0.125f;   break;
        case 2:  g = g2; H =  50; W =  50; scale = 0.0625f;  break;
        default: g = g3; H =  25; W =  25; scale = 0.03125f; break;
    }

    const int b = k >> 9;
    const u16* __restrict__ fb = g + (size_t)b * (size_t)(H * W) * CCH;
    const int rowstride = W * CCH;

    const float rx1 = bx1 * scale, ry1 = by1 * scale;
    const float rx2 = bx2 * scale, ry2 = by2 * scale;
    const float bw = fmaxf(rx2 - rx1, 1.0f) / (float)OUTHW;
    const float bh = fmaxf(ry2 - ry1, 1.0f) / (float)OUTHW;
    const float Hf = (float)H, Wf = (float)W;

    #pragma unroll
    for (int i = 0; i < 7; ++i) {
        const int pp = 2 * i + half;            // 0..13 within wave's pixel set
        const int p  = wave * 13 + pp;
        const bool act = (pp < 13) && (p < PIX);
        const int pc = act ? p : (PIX - 1);
        const int ph = pc / OUTHW;
        const int pw = pc % OUTHW;

        float acc[8] = {0, 0, 0, 0, 0, 0, 0, 0};

        #pragma unroll
        for (int sy = 0; sy < 2; ++sy) {
            const float y  = ry1 + (float)ph * bh + ((float)sy + 0.5f) * bh / 2.0f;
            const bool  vy = (y >= -1.0f) && (y <= Hf);
            const float yc = fminf(fmaxf(y, 0.0f), Hf - 1.0f);
            int yl = (int)yc; if (yl > H - 2) yl = H - 2;
            const float ly = yc - (float)yl;

            #pragma unroll
            for (int sx = 0; sx < 2; ++sx) {
                const float x  = rx1 + (float)pw * bw + ((float)sx + 0.5f) * bw / 2.0f;
                const bool  vx = (x >= -1.0f) && (x <= Wf);
                const float xc = fminf(fmaxf(x, 0.0f), Wf - 1.0f);
                int xl = (int)xc; if (xl > W - 2) xl = W - 2;
                const float lx = xc - (float)xl;

                const float v   = (vy && vx) ? 1.0f : 0.0f;
                const float w00 = (1.0f - ly) * (1.0f - lx) * v;
                const float w01 = (1.0f - ly) * lx * v;
                const float w10 = ly * (1.0f - lx) * v;
                const float w11 = ly * lx * v;

                const u16* r0 = fb + (size_t)(yl * W + xl) * CCH + c0;
                const uint4 q00 = *reinterpret_cast<const uint4*>(r0);
                const uint4 q01 = *reinterpret_cast<const uint4*>(r0 + CCH);
                const uint4 q10 = *reinterpret_cast<const uint4*>(r0 + rowstride);
                const uint4 q11 = *reinterpret_cast<const uint4*>(r0 + rowstride + CCH);

                accum8(acc, w00, q00);
                accum8(acc, w01, q01);
                accum8(acc, w10, q10);
                accum8(acc, w11, q11);
            }
        }

        if (act) {
            #pragma unroll
            for (int j = 0; j < 8; ++j)
                tile[(c0 + j) * PIX + pc] = f32_to_bf16(acc[j] * 0.25f);
        }
    }

    __syncthreads();

    // NCHW output: tile is exactly out[k] in bf16, flat c*49+p. Linear copy,
    // u32 LDS reads (2 bf16) -> vf2 dense nontemporal stores.
    vf2* __restrict__ op2 = reinterpret_cast<vf2*>(out + (size_t)k * (CCH * PIX));
    #pragma unroll
    for (int j = 0; j < 25; ++j) {
        const int f2i = j * 256 + tid;
        if (f2i < (CCH * PIX) / 2) {
            const u32 v = tilew[f2i];
            vf2 o;
            o.x = __uint_as_float(v << 16);
            o.y = __uint_as_float(v & 0xffff0000u);
            __builtin_nontemporal_store(o, &op2[f2i]);
        }
    }
}

// ===================== launch =====================
extern "C" void kernel_launch(void* const* d_in, const int* in_sizes, int n_in,
                              void* d_out, int out_size, void* d_ws, size_t ws_size,
                              hipStream_t stream) {
    const float* f0    = (const float*)d_in[0];
    const float* f1    = (const float*)d_in[1];
    const float* f2    = (const float*)d_in[2];
    const float* f3    = (const float*)d_in[3];
    const float* boxes = (const float*)d_in[4];
    float* out = (float*)d_out;

    const size_t n0 = 2ull * 200 * 200 * CCH;   // 20,480,000
    const size_t n1 = 2ull * 100 * 100 * CCH;   //  5,120,000
    const size_t n2 = 2ull *  50 *  50 * CCH;   //  1,280,000
    const size_t n3 = 2ull *  25 *  25 * CCH;   //    320,000
    const size_t need = (n0 + n1 + n2 + n3) * sizeof(u16) + KTOT * sizeof(u32);

    if (ws_size >= need) {
        u16* g0 = (u16*)d_ws;
        u16* g1 = g0 + n0;
        u16* g2 = g1 + n1;
        u16* g3 = g2 + n2;
        u32* perm = (u32*)(g3 + n3);

        stage_and_sort<<<dim3(STAGE_BLOCKS), 256, 0, stream>>>(
            f0, f1, f2, f3, g0, g1, g2, g3, boxes, perm);

        msroi_gather_bf16<<<dim3(KTOT), 256, 0, stream>>>(g0, g1, g2, g3, boxes, perm, out);
    } else {
        const int total = KTOT * CCH * PIX;
        msroi_fallback<<<(total + 255) / 256, 256, 0, stream>>>(f0, f1, f2, f3, boxes, out);
    }
}

// Round 7
// 76.629 us; speedup vs baseline: 2.9378x; 2.9378x over previous
//
#include <hip/hip_runtime.h>
#include <math.h>

// Problem constants (from reference setup_inputs)
#define BATCH   2
#define NBOX    512
#define KTOT    (BATCH * NBOX)   // 1024 ROIs
#define CCH     256
#define OUTHW   7
#define PIX     (OUTHW * OUTHW)  // 49
#define TSTR    260              // stage LDS tile stride (u16)

typedef unsigned int u32;
typedef unsigned short u16;
typedef float  vf2 __attribute__((ext_vector_type(2)));   // native vector: ok for nontemporal builtins

__device__ __forceinline__ u16 f32_to_bf16(float f) {
    u32 u = __float_as_uint(f);
    u32 r = (u + 0x7fffu + ((u >> 16) & 1u)) >> 16;   // RNE
    return (u16)r;
}

// ===================== fallback (round-1 kernel, no ws needed) =====================
__global__ __launch_bounds__(256) void msroi_fallback(
    const float* __restrict__ f0, const float* __restrict__ f1,
    const float* __restrict__ f2, const float* __restrict__ f3,
    const float* __restrict__ boxes, float* __restrict__ out)
{
    const int t = blockIdx.x * blockDim.x + threadIdx.x;
    const int total = KTOT * CCH * PIX;
    if (t >= total) return;

    const int p  = t % PIX;
    const int c  = (t / PIX) % CCH;
    const int k  = t / (PIX * CCH);
    const int ph = p / OUTHW;
    const int pw = p % OUTHW;

    const float bx1 = boxes[k * 4 + 0];
    const float by1 = boxes[k * 4 + 1];
    const float bx2 = boxes[k * 4 + 2];
    const float by2 = boxes[k * 4 + 3];

    const float area = fmaxf((bx2 - bx1) * (by2 - by1), 0.0f);
    const float s    = sqrtf(area);
    float lvlf = floorf(4.0f + log2f(s / 224.0f) + 1e-6f);
    lvlf = fminf(fmaxf(lvlf, 2.0f), 5.0f);
    const int lvl = (int)lvlf - 2;

    const float* feat; int H, W; float scale;
    switch (lvl) {
        case 0:  feat = f0; H = 200; W = 200; scale = 0.25f;    break;
        case 1:  feat = f1; H = 100; W = 100; scale = 0.125f;   break;
        case 2:  feat = f2; H =  50; W =  50; scale = 0.0625f;  break;
        default: feat = f3; H =  25; W =  25; scale = 0.03125f; break;
    }

    const int b = k / NBOX;
    const float* __restrict__ fc = feat + ((size_t)(b * CCH + c)) * (size_t)(H * W);

    const float rx1 = bx1 * scale, ry1 = by1 * scale;
    const float rx2 = bx2 * scale, ry2 = by2 * scale;
    const float bin_w = fmaxf(rx2 - rx1, 1.0f) / (float)OUTHW;
    const float bin_h = fmaxf(ry2 - ry1, 1.0f) / (float)OUTHW;
    const float Hf = (float)H, Wf = (float)W;

    float acc = 0.0f;
    #pragma unroll
    for (int sy = 0; sy < 2; ++sy) {
        const float y  = ry1 + (float)ph * bin_h + ((float)sy + 0.5f) * bin_h / 2.0f;
        const bool  vy = (y >= -1.0f) && (y <= Hf);
        const float yc = fminf(fmaxf(y, 0.0f), Hf - 1.0f);
        int yl = (int)yc; if (yl > H - 2) yl = H - 2;
        const float ly = yc - (float)yl;
        #pragma unroll
        for (int sx = 0; sx < 2; ++sx) {
            const float x  = rx1 + (float)pw * bin_w + ((float)sx + 0.5f) * bin_w / 2.0f;
            const bool  vx = (x >= -1.0f) && (x <= Wf);
            const float xc = fminf(fmaxf(x, 0.0f), Wf - 1.0f);
            int xl = (int)xc; if (xl > W - 2) xl = W - 2;
            const float lx = xc - (float)xl;
            if (vy && vx) {
                const float* p00 = fc + (size_t)yl * W + xl;
                acc += (1.0f - ly) * (1.0f - lx) * p00[0]
                     + (1.0f - ly) * lx          * p00[1]
                     + ly          * (1.0f - lx) * p00[W]
                     + ly          * lx          * p00[W + 1];
            }
        }
    }
    out[t] = acc * 0.25f;
}

// ===================== fast path =====================

// ONE kernel: blocks 0..1663 transpose NCHW fp32 -> NHWC bf16 (64-spatial x 256-ch tiles);
// block 1664 bitonic-sorts ROIs by (level, qy, qx) for L2 locality.
#define TILES_L0 625
#define TILES_L1 157
#define TILES_L2 40
#define TILES_L3 10
#define TILES_PB (TILES_L0 + TILES_L1 + TILES_L2 + TILES_L3)   // 832
#define STAGE_BLOCKS (2 * TILES_PB + 1)                        // 1665

__global__ __launch_bounds__(256) void stage_and_sort(
    const float* __restrict__ f0, const float* __restrict__ f1,
    const float* __restrict__ f2, const float* __restrict__ f3,
    u16* __restrict__ g0, u16* __restrict__ g1,
    u16* __restrict__ g2, u16* __restrict__ g3,
    const float* __restrict__ boxes, u32* __restrict__ perm)
{
    __shared__ u32 ldsw[64 * TSTR / 2];          // 33,280 B
    const int id  = (int)blockIdx.x;
    const int tid = (int)threadIdx.x;

    if (id == 2 * TILES_PB) {
        // ---- sort block ----
        u32* key = ldsw;                          // 4 KB of the tile
        for (int i = tid; i < KTOT; i += 256) {
            const float bx1 = boxes[4 * i + 0];
            const float by1 = boxes[4 * i + 1];
            const float bx2 = boxes[4 * i + 2];
            const float by2 = boxes[4 * i + 3];
            const float area = fmaxf((bx2 - bx1) * (by2 - by1), 0.0f);
            const float s    = sqrtf(area);
            float lvlf = floorf(4.0f + log2f(s / 224.0f) + 1e-6f);
            lvlf = fminf(fmaxf(lvlf, 2.0f), 5.0f);
            const u32 lvl = (u32)((int)lvlf - 2);
            const float cx = 0.5f * (bx1 + bx2);
            const float cy = 0.5f * (by1 + by2);
            const u32 qx = (u32)min(511, max(0, (int)(cx * 0.64f)));
            const u32 qy = (u32)min(511, max(0, (int)(cy * 0.64f)));
            key[i] = (lvl << 28) | (qy << 19) | (qx << 10) | (u32)i;
        }
        __syncthreads();
        for (int kk = 2; kk <= KTOT; kk <<= 1) {
            for (int j = kk >> 1; j > 0; j >>= 1) {
                for (int i = tid; i < KTOT; i += 256) {
                    const int ixj = i ^ j;
                    if (ixj > i) {
                        const u32 a = key[i], b = key[ixj];
                        const bool up = ((i & kk) == 0);
                        if ((a > b) == up) { key[i] = b; key[ixj] = a; }
                    }
                }
                __syncthreads();
            }
        }
        for (int i = tid; i < KTOT; i += 256) perm[i] = key[i] & 1023u;
        return;
    }

    // ---- transpose tile ----
    const int b = id / TILES_PB;
    const int r = id % TILES_PB;
    const float* src; u16* dst; int S, t0;
    if (r < TILES_L0)                       { src = f0; dst = g0; S = 40000; t0 = r; }
    else if (r < TILES_L0 + TILES_L1)       { src = f1; dst = g1; S = 10000; t0 = r - TILES_L0; }
    else if (r < TILES_L0 + TILES_L1 + TILES_L2) { src = f2; dst = g2; S = 2500; t0 = r - TILES_L0 - TILES_L1; }
    else                                    { src = f3; dst = g3; S = 625;  t0 = r - TILES_L0 - TILES_L1 - TILES_L2; }

    u16* tile = reinterpret_cast<u16*>(ldsw);
    const int tx = tid & 63;
    const int ty = tid >> 6;
    const int s0 = t0 * 64;
    const int s  = s0 + tx;

    if (s < S) {
        const float* sp = src + (size_t)b * CCH * (size_t)S + s;
        #pragma unroll 8
        for (int cc = 0; cc < 64; ++cc) {
            const int c = ty * 64 + cc;
            tile[tx * TSTR + c] = f32_to_bf16(__builtin_nontemporal_load(&sp[(size_t)c * S]));
        }
    }
    __syncthreads();

    u16* dp = dst + (size_t)b * (size_t)S * CCH;
    #pragma unroll
    for (int it = 0; it < 16; ++it) {
        const int row = it * 4 + ty;
        const int ss  = s0 + row;
        if (ss < S) {
            const uint2 v = reinterpret_cast<const uint2*>(tile + row * TSTR)[tx];
            reinterpret_cast<uint2*>(dp + (size_t)ss * CCH)[tx] = v;
        }
    }
}

__device__ __forceinline__ void accum8(float* acc, float w, uint4 q) {
    acc[0] = fmaf(w, __uint_as_float(q.x << 16),          acc[0]);
    acc[1] = fmaf(w, __uint_as_float(q.x & 0xffff0000u),  acc[1]);
    acc[2] = fmaf(w, __uint_as_float(q.y << 16),          acc[2]);
    acc[3] = fmaf(w, __uint_as_float(q.y & 0xffff0000u),  acc[3]);
    acc[4] = fmaf(w, __uint_as_float(q.z << 16),          acc[4]);
    acc[5] = fmaf(w, __uint_as_float(q.z & 0xffff0000u),  acc[5]);
    acc[6] = fmaf(w, __uint_as_float(q.w << 16),          acc[6]);
    acc[7] = fmaf(w, __uint_as_float(q.w & 0xffff0000u),  acc[7]);
}

// One ROI per block. Half-wave (32 lanes) = one pixel, lanes = channel octets
// (32 x 16B = full 512B NHWC bf16 row). Output transposed to NCHW via a
// channel-major bf16 LDS tile (25 KB -> 6 blocks/CU from LDS alone).
// NO launch_bounds min-waves: let regalloc keep all 16 uint4 loads in flight.
__global__ __launch_bounds__(256) void msroi_gather_bf16(
    const u16* __restrict__ g0, const u16* __restrict__ g1,
    const u16* __restrict__ g2, const u16* __restrict__ g3,
    const float* __restrict__ boxes, const u32* __restrict__ perm,
    float* __restrict__ out)
{
    __shared__ u32 tilew[(CCH * PIX) / 2];       // 25,088 B, bf16 c-major [256][49]
    u16* tile = reinterpret_cast<u16*>(tilew);

    const int bid  = (int)blockIdx.x;
    const int sidx = ((bid & 7) << 7) | (bid >> 3);   // XCD gets contiguous sorted chunk
    const int k    = (int)perm[sidx];

    const int tid  = (int)threadIdx.x;
    const int lane = tid & 63;
    const int wave = tid >> 6;
    const int half = lane >> 5;
    const int c0   = (lane & 31) * 8;   // channel octet base

    // per-ROI params (wave-uniform)
    const float bx1 = boxes[4 * k + 0];
    const float by1 = boxes[4 * k + 1];
    const float bx2 = boxes[4 * k + 2];
    const float by2 = boxes[4 * k + 3];

    const float area = fmaxf((bx2 - bx1) * (by2 - by1), 0.0f);
    const float s    = sqrtf(area);
    float lvlf = floorf(4.0f + log2f(s / 224.0f) + 1e-6f);
    lvlf = fminf(fmaxf(lvlf, 2.0f), 5.0f);
    const int lvl = (int)lvlf - 2;

    const u16* g; int H, W; float scale;
    switch (lvl) {
        case 0:  g = g0; H = 200; W = 200; scale = 0.25f;    break;
        case 1:  g = g1; H = 100; W = 100; scale = 0.125f;   break;
        case 2:  g = g2; H =  50; W =  50; scale = 0.0625f;  break;
        default: g = g3; H =  25; W =  25; scale = 0.03125f; break;
    }

    const int b = k >> 9;
    const u16* __restrict__ fb = g + (size_t)b * (size_t)(H * W) * CCH;
    const int rowstride = W * CCH;

    const float rx1 = bx1 * scale, ry1 = by1 * scale;
    const float rx2 = bx2 * scale, ry2 = by2 * scale;
    const float bw = fmaxf(rx2 - rx1, 1.0f) / (float)OUTHW;
    const float bh = fmaxf(ry2 - ry1, 1.0f) / (float)OUTHW;
    const float Hf = (float)H, Wf = (float)W;

    #pragma unroll
    for (int i = 0; i < 7; ++i) {
        const int pp = 2 * i + half;            // 0..13 within wave's pixel set
        const int p  = wave * 13 + pp;
        const bool act = (pp < 13) && (p < PIX);
        const int pc = act ? p : (PIX - 1);
        const int ph = pc / OUTHW;
        const int pw = pc % OUTHW;

        // Phase 1: geometry + ISSUE ALL 16 LOADS (no consumption yet)
        uint4 q[16];
        float wv[16];
        #pragma unroll
        for (int sy = 0; sy < 2; ++sy) {
            const float y  = ry1 + (float)ph * bh + ((float)sy + 0.5f) * bh / 2.0f;
            const bool  vy = (y >= -1.0f) && (y <= Hf);
            const float yc = fminf(fmaxf(y, 0.0f), Hf - 1.0f);
            int yl = (int)yc; if (yl > H - 2) yl = H - 2;
            const float ly = yc - (float)yl;

            #pragma unroll
            for (int sx = 0; sx < 2; ++sx) {
                const float x  = rx1 + (float)pw * bw + ((float)sx + 0.5f) * bw / 2.0f;
                const bool  vx = (x >= -1.0f) && (x <= Wf);
                const float xc = fminf(fmaxf(x, 0.0f), Wf - 1.0f);
                int xl = (int)xc; if (xl > W - 2) xl = W - 2;
                const float lx = xc - (float)xl;

                const float v   = (vy && vx) ? 1.0f : 0.0f;
                const int   si  = sy * 2 + sx;
                wv[si * 4 + 0] = (1.0f - ly) * (1.0f - lx) * v;
                wv[si * 4 + 1] = (1.0f - ly) * lx * v;
                wv[si * 4 + 2] = ly * (1.0f - lx) * v;
                wv[si * 4 + 3] = ly * lx * v;

                const u16* r0 = fb + (size_t)(yl * W + xl) * CCH + c0;
                q[si * 4 + 0] = *reinterpret_cast<const uint4*>(r0);
                q[si * 4 + 1] = *reinterpret_cast<const uint4*>(r0 + CCH);
                q[si * 4 + 2] = *reinterpret_cast<const uint4*>(r0 + rowstride);
                q[si * 4 + 3] = *reinterpret_cast<const uint4*>(r0 + rowstride + CCH);
            }
        }

        // Phase 2: consume
        float acc[8] = {0, 0, 0, 0, 0, 0, 0, 0};
        #pragma unroll
        for (int j = 0; j < 16; ++j) accum8(acc, wv[j], q[j]);

        if (act) {
            #pragma unroll
            for (int j = 0; j < 8; ++j)
                tile[(c0 + j) * PIX + pc] = f32_to_bf16(acc[j] * 0.25f);
        }
    }

    __syncthreads();

    // NCHW output: tile is exactly out[k] in bf16, flat c*49+p. Linear copy,
    // u32 LDS reads (2 bf16) -> vf2 dense nontemporal stores.
    vf2* __restrict__ op2 = reinterpret_cast<vf2*>(out + (size_t)k * (CCH * PIX));
    #pragma unroll
    for (int j = 0; j < 25; ++j) {
        const int f2i = j * 256 + tid;
        if (f2i < (CCH * PIX) / 2) {
            const u32 v = tilew[f2i];
            vf2 o;
            o.x = __uint_as_float(v << 16);
            o.y = __uint_as_float(v & 0xffff0000u);
            __builtin_nontemporal_store(o, &op2[f2i]);
        }
    }
}

// ===================== launch =====================
extern "C" void kernel_launch(void* const* d_in, const int* in_sizes, int n_in,
                              void* d_out, int out_size, void* d_ws, size_t ws_size,
                              hipStream_t stream) {
    const float* f0    = (const float*)d_in[0];
    const float* f1    = (const float*)d_in[1];
    const float* f2    = (const float*)d_in[2];
    const float* f3    = (const float*)d_in[3];
    const float* boxes = (const float*)d_in[4];
    float* out = (float*)d_out;

    const size_t n0 = 2ull * 200 * 200 * CCH;   // 20,480,000
    const size_t n1 = 2ull * 100 * 100 * CCH;   //  5,120,000
    const size_t n2 = 2ull *  50 *  50 * CCH;   //  1,280,000
    const size_t n3 = 2ull *  25 *  25 * CCH;   //    320,000
    const size_t need = (n0 + n1 + n2 + n3) * sizeof(u16) + KTOT * sizeof(u32);

    if (ws_size >= need) {
        u16* g0 = (u16*)d_ws;
        u16* g1 = g0 + n0;
        u16* g2 = g1 + n1;
        u16* g3 = g2 + n2;
        u32* perm = (u32*)(g3 + n3);

        stage_and_sort<<<dim3(STAGE_BLOCKS), 256, 0, stream>>>(
            f0, f1, f2, f3, g0, g1, g2, g3, boxes, perm);

        msroi_gather_bf16<<<dim3(KTOT), 256, 0, stream>>>(g0, g1, g2, g3, boxes, perm, out);
    } else {
        const int total = KTOT * CCH * PIX;
        msroi_fallback<<<(total + 255) / 256, 256, 0, stream>>>(f0, f1, f2, f3, boxes, out);
    }
}